// Round 12
// baseline (1114.113 us; speedup 1.0000x reference)
//
#include <hip/hip_runtime.h>
#include <hip/hip_cooperative_groups.h>

namespace cg = cooperative_groups;

#define IMG 256
#define TSZ 128
#define TPB 128
#define TILES 2
#define NIMG 8
#define NBLK (NIMG * TILES * TILES)

// ctrl layout (unsigned words), zeroed via hipMemsetAsync before each launch:
// [0..23] recon convergence tags tag[img][rc]; [24..31] per-image barrier
// counters; [32] any1; [33] any0; [34..41] CC per image; [42] done counter
#define CTRL_WORDS 64

// Swizzle: row r, col c -> r*128 + (c ^ (r&30)). Bit0 of the XOR is clear, so
// even/odd column pairs stay contiguous+8B-aligned for ds_read_b64 in the H
// phase; V-phase column walks remain a bank permutation (2-way, free).
__device__ __forceinline__ int swz(int r, int c) { return r * TSZ + (c ^ (r & 30)); }

__device__ __forceinline__ float agload(const float* p) {
  return __hip_atomic_load(p, __ATOMIC_RELAXED, __HIP_MEMORY_SCOPE_AGENT);
}
__device__ __forceinline__ void agstore(float* p, float v) {
  __hip_atomic_store(p, v, __ATOMIC_RELAXED, __HIP_MEMORY_SCOPE_AGENT);
}
__device__ __forceinline__ unsigned agloadu(const unsigned* p) {
  return __hip_atomic_load(p, __ATOMIC_RELAXED, __HIP_MEMORY_SCOPE_AGENT);
}

// 4-party per-image barrier: fence / arrive / spin / fence (r9-proven).
__device__ __forceinline__ void img_barrier(unsigned* bar, unsigned& gen, int tid) {
  __threadfence();
  __syncthreads();
  ++gen;
  if (tid == 0) {
    __hip_atomic_fetch_add(bar, 1u, __ATOMIC_RELAXED, __HIP_MEMORY_SCOPE_AGENT);
    while (__hip_atomic_load(bar, __ATOMIC_RELAXED, __HIP_MEMORY_SCOPE_AGENT) < 4u * gen)
      __builtin_amdgcn_s_sleep(1);
  }
  __syncthreads();
  __threadfence();
}

// Geodesic reconstruction by dilation to exact fixpoint (r8/r9-proven sweeps,
// b64-paired H phase). Coverage per iteration: H-fwd {W,N,S,NW,SW} + H-bwd
// {E,N,S,NE,SE} = all 8 neighbors (racy-but-monotone reads <= fixpoint), so a
// no-change iteration certifies the true fixpoint. V sweeps accelerate
// vertical propagation. rimg: published rec (full image) for halo exchange.
__device__ void recon(float* recS, float* maskS,
                      float* topH, float* botH, float* leftH, float* rightH,
                      float* corn, float* rimg, unsigned* tag,
                      unsigned* bar, unsigned& gen,
                      int R0, int C0, int tid, int* blkflag) {
  const float NEGF = -__builtin_inff();
  for (unsigned it = 1;; ++it) {
    // ---- stage halos from published rec (fixed for this iteration) ----
    {
      int c = C0 + tid;
      topH[tid]  = (R0 > 0)         ? agload(&rimg[(R0 - 1) * IMG + c]) : NEGF;
      botH[tid]  = (R0 + TSZ < IMG) ? agload(&rimg[(R0 + TSZ) * IMG + c]) : NEGF;
      leftH[tid]  = (C0 > 0)         ? agload(&rimg[(R0 + tid) * IMG + C0 - 1]) : NEGF;
      rightH[tid] = (C0 + TSZ < IMG) ? agload(&rimg[(R0 + tid) * IMG + C0 + TSZ]) : NEGF;
    }
    if (tid < 4) {  // corners: [0]=TL [1]=TR [2]=BL [3]=BR
      int rr = (tid & 2) ? R0 + TSZ : R0 - 1;
      int cc = (tid & 1) ? C0 + TSZ : C0 - 1;
      corn[tid] = (rr >= 0 && rr < IMG && cc >= 0 && cc < IMG)
                  ? agload(&rimg[rr * IMG + cc]) : NEGF;
    }
    if (tid == 0) *blkflag = 0;
    __syncthreads();

    bool chg = false;
    // ======== H phase: lane owns row r = tid; b64-paired chunk-of-16 ======
    {
      const int r = tid;
      const int xs = r & 30;
      float* rowS = &recS[r * TSZ];
      const float* mrow = &maskS[r * TSZ];
      const float* upB = (r == 0)       ? topH : &recS[(r - 1) * TSZ];
      const int upX    = (r == 0)       ? 0    : ((r - 1) & 30);
      const float* dnB = (r == TSZ - 1) ? botH : &recS[(r + 1) * TSZ];
      const int dnX    = (r == TSZ - 1) ? 0    : ((r + 1) & 30);
      // forward: W(carry) + N,S + NW,SW (pu/pd = prev-column up/dn)
      {
        float carry = leftH[r];
        float pu = (r == 0)       ? corn[0] : leftH[r - 1];
        float pd = (r == TSZ - 1) ? corn[2] : leftH[r + 1];
#pragma unroll 1
        for (int k = 0; k < 8; ++k) {
          const int c0 = k * 16;
          float o[16], mm[16], uu[16], dd[16];
#pragma unroll
          for (int j = 0; j < 8; ++j) {
            const int cc = c0 + 2 * j;
            float2 po  = *(const float2*)&rowS[cc ^ xs];
            float2 pm  = *(const float2*)&mrow[cc ^ xs];
            float2 pu2 = *(const float2*)&upB[cc ^ upX];
            float2 pd2 = *(const float2*)&dnB[cc ^ dnX];
            o[2*j] = po.x;   o[2*j+1] = po.y;
            mm[2*j] = pm.x;  mm[2*j+1] = pm.y;
            uu[2*j] = pu2.x; uu[2*j+1] = pu2.y;
            dd[2*j] = pd2.x; dd[2*j+1] = pd2.y;
          }
#pragma unroll
          for (int i = 0; i < 16; ++i) {
            float cand = fmaxf(fmaxf(fmaxf(uu[i], dd[i]), fmaxf(pu, pd)), carry);
            float v = fminf(mm[i], fmaxf(o[i], cand));
            chg |= (v > o[i]);
            o[i] = v; carry = v; pu = uu[i]; pd = dd[i];
          }
#pragma unroll
          for (int j = 0; j < 8; ++j) {
            const int cc = c0 + 2 * j;
            float2 w; w.x = o[2*j]; w.y = o[2*j+1];
            *(float2*)&rowS[cc ^ xs] = w;
          }
        }
      }
      // backward: E(carry) + N,S + NE,SE
      {
        float carry = rightH[r];
        float pu = (r == 0)       ? corn[1] : rightH[r - 1];
        float pd = (r == TSZ - 1) ? corn[3] : rightH[r + 1];
#pragma unroll 1
        for (int k = 7; k >= 0; --k) {
          const int c0 = k * 16;
          float o[16], mm[16], uu[16], dd[16];
#pragma unroll
          for (int j = 0; j < 8; ++j) {
            const int cc = c0 + 2 * j;
            float2 po  = *(const float2*)&rowS[cc ^ xs];
            float2 pm  = *(const float2*)&mrow[cc ^ xs];
            float2 pu2 = *(const float2*)&upB[cc ^ upX];
            float2 pd2 = *(const float2*)&dnB[cc ^ dnX];
            o[2*j] = po.x;   o[2*j+1] = po.y;
            mm[2*j] = pm.x;  mm[2*j+1] = pm.y;
            uu[2*j] = pu2.x; uu[2*j+1] = pu2.y;
            dd[2*j] = pd2.x; dd[2*j+1] = pd2.y;
          }
#pragma unroll
          for (int i = 15; i >= 0; --i) {
            float cand = fmaxf(fmaxf(fmaxf(uu[i], dd[i]), fmaxf(pu, pd)), carry);
            float v = fminf(mm[i], fmaxf(o[i], cand));
            chg |= (v > o[i]);
            o[i] = v; carry = v; pu = uu[i]; pd = dd[i];
          }
#pragma unroll
          for (int j = 0; j < 8; ++j) {
            const int cc = c0 + 2 * j;
            float2 w; w.x = o[2*j]; w.y = o[2*j+1];
            *(float2*)&rowS[cc ^ xs] = w;
          }
        }
      }
    }
    __syncthreads();
    // ======== V phase: lane owns column c = tid; chunk-of-16 (r9) ========
    {
      const int c = tid;
      // forward (top -> bottom): N via live carry
      {
        float carry = topH[c];
#pragma unroll 1
        for (int k = 0; k < 8; ++k) {
          const int r0i = k * 16;
          float o[16], mm[16];
#pragma unroll
          for (int i = 0; i < 16; ++i) {
            o[i]  = recS[swz(r0i + i, c)];
            mm[i] = maskS[swz(r0i + i, c)];
          }
#pragma unroll
          for (int i = 0; i < 16; ++i) {
            float v = fminf(mm[i], fmaxf(o[i], carry));
            chg |= (v > o[i]);
            o[i] = v; carry = v;
          }
#pragma unroll
          for (int i = 0; i < 16; ++i) recS[swz(r0i + i, c)] = o[i];
        }
      }
      // backward (bottom -> top): S via live carry
      {
        float carry = botH[c];
#pragma unroll 1
        for (int k = 7; k >= 0; --k) {
          const int r0i = k * 16;
          float o[16], mm[16];
#pragma unroll
          for (int i = 0; i < 16; ++i) {
            o[i]  = recS[swz(r0i + i, c)];
            mm[i] = maskS[swz(r0i + i, c)];
          }
#pragma unroll
          for (int i = 15; i >= 0; --i) {
            float v = fminf(mm[i], fmaxf(o[i], carry));
            chg |= (v > o[i]);
            o[i] = v; carry = v;
          }
#pragma unroll
          for (int i = 0; i < 16; ++i) recS[swz(r0i + i, c)] = o[i];
        }
      }
    }
    __syncthreads();

    // ---- r9-proven vote + ring publish + per-image convergence ----
    if (__any(chg ? 1 : 0) && (tid & 63) == 0) *blkflag = 1;
    __syncthreads();
    if (*blkflag) {
      agstore(&rimg[R0 * IMG + C0 + tid],              recS[swz(0, tid)]);
      agstore(&rimg[(R0 + TSZ - 1) * IMG + C0 + tid],  recS[swz(TSZ - 1, tid)]);
      agstore(&rimg[(R0 + tid) * IMG + C0],            recS[swz(tid, 0)]);
      agstore(&rimg[(R0 + tid) * IMG + C0 + TSZ - 1],  recS[swz(tid, TSZ - 1)]);
      if (tid == 0) atomicMax(tag, it);
    }
    img_barrier(bar, gen, tid);
    if (agloadu(tag) < it) break;  // uniform within image: tag>=it only if change
  }
}

__global__ void __launch_bounds__(TPB)
hmax_kernel(const float* __restrict__ x, const float* __restrict__ hvec,
            const float* __restrict__ u, float* __restrict__ out,
            float* rec_g, unsigned* ctrl) {
  extern __shared__ float lds[];
  float* recS   = lds;
  float* maskS  = lds + TSZ * TSZ;
  float* topH   = lds + 2 * TSZ * TSZ;
  float* botH   = topH + TSZ;
  float* leftH  = botH + TSZ;
  float* rightH = leftH + TSZ;
  float* corn   = rightH + TSZ;
  __shared__ int blkflag;

  const int tid = threadIdx.x;
  const int blk = blockIdx.x;
  const int img = blk / (TILES * TILES);
  const int tin = blk % (TILES * TILES);
  const int ty = tin / TILES, tx = tin % TILES;
  const int R0 = ty * TSZ, C0 = tx * TSZ;
  const float* ximg = x + (size_t)img * IMG * IMG;
  const float* uimg = u + (size_t)img * IMG * IMG;
  float* rimg = rec_g + (size_t)img * IMG * IMG;
  unsigned* tag = &ctrl[img * 3];
  unsigned* bar = &ctrl[24 + img];
  unsigned gen = 0;

  // ---- init: mask = x, rec = x - h (LDS), publish ring ----
  const float hval = hvec[img];
  for (int rr = 0; rr < TSZ; ++rr) {
    float xv = ximg[(R0 + rr) * IMG + C0 + tid];
    maskS[swz(rr, tid)] = xv;
    recS[swz(rr, tid)] = xv - hval;
  }
  __syncthreads();
  agstore(&rimg[R0 * IMG + C0 + tid],              recS[swz(0, tid)]);
  agstore(&rimg[(R0 + TSZ - 1) * IMG + C0 + tid],  recS[swz(TSZ - 1, tid)]);
  agstore(&rimg[(R0 + tid) * IMG + C0],            recS[swz(tid, 0)]);
  agstore(&rimg[(R0 + tid) * IMG + C0 + TSZ - 1],  recS[swz(tid, TSZ - 1)]);
  img_barrier(bar, gen, tid);

  // ---- recon 1: xh = rho(x - h | x) ----
  recon(recS, maskS, topH, botH, leftH, rightH, corn, rimg, &tag[0], bar, gen,
        R0, C0, tid, &blkflag);

  // ---- phase B: mask = xh, rec = xh - EPS, publish ring ----
  for (int rr = 0; rr < TSZ; ++rr) {
    int ix = swz(rr, tid);
    float xh = recS[ix];
    maskS[ix] = xh;
    recS[ix] = xh - 1e-05f;
  }
  __syncthreads();
  agstore(&rimg[R0 * IMG + C0 + tid],              recS[swz(0, tid)]);
  agstore(&rimg[(R0 + TSZ - 1) * IMG + C0 + tid],  recS[swz(TSZ - 1, tid)]);
  agstore(&rimg[(R0 + tid) * IMG + C0],            recS[swz(tid, 0)]);
  agstore(&rimg[(R0 + tid) * IMG + C0 + TSZ - 1],  recS[swz(tid, TSZ - 1)]);
  img_barrier(bar, gen, tid);

  // ---- recon 2: rho(xh - EPS | xh) ----
  recon(recS, maskS, topH, botH, leftH, rightH, corn, rimg, &tag[1], bar, gen,
        R0, C0, tid, &blkflag);

  // ---- phase C: Rmax, marker = min(U, Rmax), publish ring ----
  bool a1 = false, a0 = false;
  for (int rr = 0; rr < TSZ; ++rr) {
    int ix = swz(rr, tid);
    float xh = maskS[ix];
    float r2 = recS[ix];
    float rm = (xh - r2 > 0.0f) ? 1.0f : 0.0f;
    a1 |= (rm == 1.0f);
    a0 |= (rm == 0.0f);
    float uv = uimg[(R0 + rr) * IMG + C0 + tid] / 100.0f;
    maskS[ix] = rm;
    recS[ix] = fminf(uv, rm);
  }
  if (__any(a1 ? 1 : 0) && (tid & 63) == 0)
    __hip_atomic_fetch_or(&ctrl[32], 1u, __ATOMIC_RELAXED, __HIP_MEMORY_SCOPE_AGENT);
  if (__any(a0 ? 1 : 0) && (tid & 63) == 0)
    __hip_atomic_fetch_or(&ctrl[33], 1u, __ATOMIC_RELAXED, __HIP_MEMORY_SCOPE_AGENT);
  __syncthreads();
  agstore(&rimg[R0 * IMG + C0 + tid],              recS[swz(0, tid)]);
  agstore(&rimg[(R0 + TSZ - 1) * IMG + C0 + tid],  recS[swz(TSZ - 1, tid)]);
  agstore(&rimg[(R0 + tid) * IMG + C0],            recS[swz(tid, 0)]);
  agstore(&rimg[(R0 + tid) * IMG + C0 + TSZ - 1],  recS[swz(tid, TSZ - 1)]);
  img_barrier(bar, gen, tid);

  // ---- recon 3: R = rho(min(U, Rmax) | Rmax) ----
  recon(recS, maskS, topH, botH, leftH, rightH, corn, rimg, &tag[2], bar, gen,
        R0, C0, tid, &blkflag);

  // ---- phase D: count U == R per image ----
  unsigned cnt = 0;
  for (int rr = 0; rr < TSZ; ++rr) {
    float Rv = recS[swz(rr, tid)];
    float uv = uimg[(R0 + rr) * IMG + C0 + tid] / 100.0f;
    cnt += (uv == Rv) ? 1u : 0u;
  }
  for (int off = 32; off > 0; off >>= 1) cnt += __shfl_down(cnt, off, 64);
  if ((tid & 63) == 0)
    __hip_atomic_fetch_add(&ctrl[34 + img], cnt, __ATOMIC_RELAXED, __HIP_MEMORY_SCOPE_AGENT);
  img_barrier(bar, gen, tid);  // all 4 blocks' CC adds done

  if (tin == 0 && tid == 0)
    __hip_atomic_fetch_add(&ctrl[42], 1u, __ATOMIC_RELEASE, __HIP_MEMORY_SCOPE_AGENT);

  // ---- final join + output (block 0 only; co-resident via coop launch) ----
  if (blk == 0) {
    if (tid == 0) {
      while (__hip_atomic_load(&ctrl[42], __ATOMIC_RELAXED, __HIP_MEMORY_SCOPE_AGENT) < NIMG)
        __builtin_amdgcn_s_sleep(1);
    }
    __syncthreads();
    __threadfence();
    if (tid < NIMG) {
      float CC = (float)agloadu(&ctrl[34 + tid]);
      float gmax = agloadu(&ctrl[32]) ? 1.0f : 0.0f;
      float gmin = agloadu(&ctrl[33]) ? 0.0f : 1.0f;
      float d = gmax - gmin;
      out[tid] = fminf(CC, 100.0f * d * CC);
    }
  }
}

extern "C" void kernel_launch(void* const* d_in, const int* in_sizes, int n_in,
                              void* d_out, int out_size, void* d_ws, size_t ws_size,
                              hipStream_t stream) {
  const float* x = (const float*)d_in[0];
  const float* h = (const float*)d_in[1];
  const float* u = (const float*)d_in[2];
  float* out = (float*)d_out;
  float* rec_g = (float*)d_ws;
  unsigned* ctrl = (unsigned*)((char*)d_ws + (size_t)NIMG * IMG * IMG * sizeof(float));

  hipMemsetAsync(ctrl, 0, CTRL_WORDS * sizeof(unsigned), stream);

  const unsigned SH = (2 * TSZ * TSZ + 4 * TSZ + 4) * sizeof(float);
  hipFuncSetAttribute((const void*)hmax_kernel,
                      hipFuncAttributeMaxDynamicSharedMemorySize, (int)SH);

  void* args[] = { (void*)&x, (void*)&h, (void*)&u, (void*)&out,
                   (void*)&rec_g, (void*)&ctrl };
  hipLaunchCooperativeKernel((void*)hmax_kernel, dim3(NBLK), dim3(TPB),
                             args, SH, stream);
}

// Round 13
// 443.649 us; speedup vs baseline: 2.5112x; 2.5112x over previous
//
#include <hip/hip_runtime.h>

#define IMG 256
#define TSZ 64
#define TPB 64
#define TILES 4
#define NIMG 8
#define NTIL (TILES * TILES)
#define NBLK (NIMG * NTIL)

// ctrl layout (unsigned words), zeroed via hipMemsetAsync before each launch:
// [0..23] recon convergence tags tag[img][rc]; [24..31] per-image barrier
// counters; [32] any1; [33] any0; [34..41] CC per image; [42] done counter
#define CTRL_WORDS 64

// Swizzle: row r, col c -> r*64 + (c ^ (r&31)). Row walks and column walks
// both land <=2-way on the 32 banks (free on CDNA4 per m136).
__device__ __forceinline__ int swz(int r, int c) { return r * TSZ + (c ^ (r & 31)); }

__device__ __forceinline__ float agload(const float* p) {
  return __hip_atomic_load(p, __ATOMIC_RELAXED, __HIP_MEMORY_SCOPE_AGENT);
}
__device__ __forceinline__ void agstore(float* p, float v) {
  __hip_atomic_store(p, v, __ATOMIC_RELAXED, __HIP_MEMORY_SCOPE_AGENT);
}
__device__ __forceinline__ unsigned agloadu(const unsigned* p) {
  return __hip_atomic_load(p, __ATOMIC_RELAXED, __HIP_MEMORY_SCOPE_AGENT);
}

// 16-party per-image barrier: fence / arrive / spin / fence (r9-proven shape).
__device__ __forceinline__ void img_barrier(unsigned* bar, unsigned& gen, int tid) {
  __threadfence();
  __syncthreads();
  ++gen;
  if (tid == 0) {
    __hip_atomic_fetch_add(bar, 1u, __ATOMIC_RELAXED, __HIP_MEMORY_SCOPE_AGENT);
    while (__hip_atomic_load(bar, __ATOMIC_RELAXED, __HIP_MEMORY_SCOPE_AGENT) < (unsigned)NTIL * gen)
      __builtin_amdgcn_s_sleep(1);
  }
  __syncthreads();
  __threadfence();
}

// Geodesic reconstruction by dilation to exact fixpoint (r8/r9-proven sweeps).
// Coverage per iteration: H-fwd {W,N,S,NW,SW} + H-bwd {E,N,S,NE,SE} = all 8
// neighbors (racy-but-monotone reads <= fixpoint), so a no-change iteration
// certifies the true fixpoint. V sweeps accelerate vertical propagation.
// rimg: published rec (full image) for halo exchange (boundary rings only).
__device__ void recon(float* recS, float* maskS,
                      float* topH, float* botH, float* leftH, float* rightH,
                      float* rimg, unsigned* tag, unsigned* bar, unsigned& gen,
                      int R0, int C0, int tid, int* blkflag) {
  const float NEGF = -__builtin_inff();
  for (unsigned it = 1;; ++it) {
    // ---- stage halos from published rec (fixed for this iteration) ----
    for (int i = tid; i < TSZ + 2; i += TPB) {
      int c = C0 + i - 1;
      int rT = R0 - 1, rB = R0 + TSZ;
      bool cok = (c >= 0 && c < IMG);
      topH[i] = (cok && rT >= 0)  ? agload(&rimg[rT * IMG + c]) : NEGF;
      botH[i] = (cok && rB < IMG) ? agload(&rimg[rB * IMG + c]) : NEGF;
    }
    for (int i = tid; i < TSZ; i += TPB) {
      int r = R0 + i;
      leftH[i]  = (C0 > 0)         ? agload(&rimg[r * IMG + C0 - 1])   : NEGF;
      rightH[i] = (C0 + TSZ < IMG) ? agload(&rimg[r * IMG + C0 + TSZ]) : NEGF;
    }
    __syncthreads();

    bool chg = false;
    // ======== H phase: lane owns row r = tid; chunk-of-16 buffered ======
    {
      const int r = tid;
      const int xs = r & 31;
      float* rowS = &recS[r * TSZ];
      const float* mrow = &maskS[r * TSZ];
      const float* upB = (r == 0)       ? &topH[1] : &recS[(r - 1) * TSZ];
      const int upX    = (r == 0)       ? 0        : ((r - 1) & 31);
      const float* dnB = (r == TSZ - 1) ? &botH[1] : &recS[(r + 1) * TSZ];
      const int dnX    = (r == TSZ - 1) ? 0        : ((r + 1) & 31);
      // forward: W(carry) + N,S + NW,SW (pu/pd = prev-column up/dn)
      {
        float carry = leftH[r];
        float pu = (r == 0)       ? topH[0] : leftH[r - 1];
        float pd = (r == TSZ - 1) ? botH[0] : leftH[r + 1];
#pragma unroll 1
        for (int k = 0; k < TSZ / 16; ++k) {
          const int c0 = k * 16;
          float o[16], mm[16], uu[16], dd[16];
#pragma unroll
          for (int i = 0; i < 16; ++i) {
            o[i]  = rowS[(c0 + i) ^ xs];
            mm[i] = mrow[(c0 + i) ^ xs];
            uu[i] = upB[(c0 + i) ^ upX];
            dd[i] = dnB[(c0 + i) ^ dnX];
          }
#pragma unroll
          for (int i = 0; i < 16; ++i) {
            float cand = fmaxf(fmaxf(fmaxf(uu[i], dd[i]), fmaxf(pu, pd)), carry);
            float v = fminf(mm[i], fmaxf(o[i], cand));
            chg |= (v > o[i]);
            o[i] = v; carry = v; pu = uu[i]; pd = dd[i];
          }
#pragma unroll
          for (int i = 0; i < 16; ++i) rowS[(c0 + i) ^ xs] = o[i];
        }
      }
      // backward: E(carry) + N,S + NE,SE
      {
        float carry = rightH[r];
        float pu = (r == 0)       ? topH[TSZ + 1] : rightH[r - 1];
        float pd = (r == TSZ - 1) ? botH[TSZ + 1] : rightH[r + 1];
#pragma unroll 1
        for (int k = TSZ / 16 - 1; k >= 0; --k) {
          const int c0 = k * 16;
          float o[16], mm[16], uu[16], dd[16];
#pragma unroll
          for (int i = 0; i < 16; ++i) {
            o[i]  = rowS[(c0 + i) ^ xs];
            mm[i] = mrow[(c0 + i) ^ xs];
            uu[i] = upB[(c0 + i) ^ upX];
            dd[i] = dnB[(c0 + i) ^ dnX];
          }
#pragma unroll
          for (int i = 15; i >= 0; --i) {
            float cand = fmaxf(fmaxf(fmaxf(uu[i], dd[i]), fmaxf(pu, pd)), carry);
            float v = fminf(mm[i], fmaxf(o[i], cand));
            chg |= (v > o[i]);
            o[i] = v; carry = v; pu = uu[i]; pd = dd[i];
          }
#pragma unroll
          for (int i = 0; i < 16; ++i) rowS[(c0 + i) ^ xs] = o[i];
        }
      }
    }
    __syncthreads();
    // ======== V phase: lane owns column c = tid; chunk-of-16 buffered ====
    {
      const int c = tid;
      // forward (top -> bottom): N via live carry
      {
        float carry = topH[c + 1];
#pragma unroll 1
        for (int k = 0; k < TSZ / 16; ++k) {
          const int r0i = k * 16;
          float o[16], mm[16];
#pragma unroll
          for (int i = 0; i < 16; ++i) {
            o[i]  = recS[swz(r0i + i, c)];
            mm[i] = maskS[swz(r0i + i, c)];
          }
#pragma unroll
          for (int i = 0; i < 16; ++i) {
            float v = fminf(mm[i], fmaxf(o[i], carry));
            chg |= (v > o[i]);
            o[i] = v; carry = v;
          }
#pragma unroll
          for (int i = 0; i < 16; ++i) recS[swz(r0i + i, c)] = o[i];
        }
      }
      // backward (bottom -> top): S via live carry
      {
        float carry = botH[c + 1];
#pragma unroll 1
        for (int k = TSZ / 16 - 1; k >= 0; --k) {
          const int r0i = k * 16;
          float o[16], mm[16];
#pragma unroll
          for (int i = 0; i < 16; ++i) {
            o[i]  = recS[swz(r0i + i, c)];
            mm[i] = maskS[swz(r0i + i, c)];
          }
#pragma unroll
          for (int i = 15; i >= 0; --i) {
            float v = fminf(mm[i], fmaxf(o[i], carry));
            chg |= (v > o[i]);
            o[i] = v; carry = v;
          }
#pragma unroll
          for (int i = 0; i < 16; ++i) recS[swz(r0i + i, c)] = o[i];
        }
      }
    }
    __syncthreads();

    // ---- r9-proven vote + ring publish + per-image convergence ----
    if (tid == 0) *blkflag = 0;
    __syncthreads();
    if (__any(chg ? 1 : 0) && (tid & 63) == 0) *blkflag = 1;
    __syncthreads();
    if (*blkflag) {
      agstore(&rimg[R0 * IMG + C0 + tid],              recS[swz(0, tid)]);
      agstore(&rimg[(R0 + TSZ - 1) * IMG + C0 + tid],  recS[swz(TSZ - 1, tid)]);
      agstore(&rimg[(R0 + tid) * IMG + C0],            recS[swz(tid, 0)]);
      agstore(&rimg[(R0 + tid) * IMG + C0 + TSZ - 1],  recS[swz(tid, TSZ - 1)]);
      if (tid == 0) atomicMax(tag, it);
    }
    img_barrier(bar, gen, tid);
    if (agloadu(tag) < it) break;  // uniform within image: tag>=it only if change
  }
}

__global__ void __launch_bounds__(TPB)
hmax_kernel(const float* __restrict__ x, const float* __restrict__ hvec,
            const float* __restrict__ u, float* __restrict__ out,
            float* rec_g, unsigned* ctrl) {
  extern __shared__ float lds[];
  float* recS   = lds;
  float* maskS  = lds + TSZ * TSZ;
  float* topH   = lds + 2 * TSZ * TSZ;
  float* botH   = topH + (TSZ + 2);
  float* leftH  = botH + (TSZ + 2);
  float* rightH = leftH + TSZ;
  __shared__ int blkflag;

  const int tid = threadIdx.x;
  const int blk = blockIdx.x;
  const int img = blk / NTIL;
  const int tin = blk % NTIL;
  const int ty = tin / TILES, tx = tin % TILES;
  const int R0 = ty * TSZ, C0 = tx * TSZ;
  const float* ximg = x + (size_t)img * IMG * IMG;
  const float* uimg = u + (size_t)img * IMG * IMG;
  float* rimg = rec_g + (size_t)img * IMG * IMG;
  unsigned* tag = &ctrl[img * 3];
  unsigned* bar = &ctrl[24 + img];
  unsigned gen = 0;

  // ---- init: mask = x, rec = x - h (LDS), publish ring ----
  const float hval = hvec[img];
  for (int rr = 0; rr < TSZ; ++rr) {
    float xv = ximg[(R0 + rr) * IMG + C0 + tid];
    maskS[swz(rr, tid)] = xv;
    recS[swz(rr, tid)] = xv - hval;
  }
  __syncthreads();
  agstore(&rimg[R0 * IMG + C0 + tid],              recS[swz(0, tid)]);
  agstore(&rimg[(R0 + TSZ - 1) * IMG + C0 + tid],  recS[swz(TSZ - 1, tid)]);
  agstore(&rimg[(R0 + tid) * IMG + C0],            recS[swz(tid, 0)]);
  agstore(&rimg[(R0 + tid) * IMG + C0 + TSZ - 1],  recS[swz(tid, TSZ - 1)]);
  img_barrier(bar, gen, tid);

  // ---- recon 1: xh = rho(x - h | x) ----
  recon(recS, maskS, topH, botH, leftH, rightH, rimg, &tag[0], bar, gen,
        R0, C0, tid, &blkflag);

  // ---- phase B: mask = xh, rec = xh - EPS, publish ring ----
  for (int rr = 0; rr < TSZ; ++rr) {
    int ix = swz(rr, tid);
    float xh = recS[ix];
    maskS[ix] = xh;
    recS[ix] = xh - 1e-05f;
  }
  __syncthreads();
  agstore(&rimg[R0 * IMG + C0 + tid],              recS[swz(0, tid)]);
  agstore(&rimg[(R0 + TSZ - 1) * IMG + C0 + tid],  recS[swz(TSZ - 1, tid)]);
  agstore(&rimg[(R0 + tid) * IMG + C0],            recS[swz(tid, 0)]);
  agstore(&rimg[(R0 + tid) * IMG + C0 + TSZ - 1],  recS[swz(tid, TSZ - 1)]);
  img_barrier(bar, gen, tid);

  // ---- recon 2: rho(xh - EPS | xh) ----
  recon(recS, maskS, topH, botH, leftH, rightH, rimg, &tag[1], bar, gen,
        R0, C0, tid, &blkflag);

  // ---- phase C: Rmax, marker = min(U, Rmax), publish ring ----
  bool a1 = false, a0 = false;
  for (int rr = 0; rr < TSZ; ++rr) {
    int ix = swz(rr, tid);
    float xh = maskS[ix];
    float r2 = recS[ix];
    float rm = (xh - r2 > 0.0f) ? 1.0f : 0.0f;
    a1 |= (rm == 1.0f);
    a0 |= (rm == 0.0f);
    float uv = uimg[(R0 + rr) * IMG + C0 + tid] / 100.0f;
    maskS[ix] = rm;
    recS[ix] = fminf(uv, rm);
  }
  if (__any(a1 ? 1 : 0) && (tid & 63) == 0)
    __hip_atomic_fetch_or(&ctrl[32], 1u, __ATOMIC_RELAXED, __HIP_MEMORY_SCOPE_AGENT);
  if (__any(a0 ? 1 : 0) && (tid & 63) == 0)
    __hip_atomic_fetch_or(&ctrl[33], 1u, __ATOMIC_RELAXED, __HIP_MEMORY_SCOPE_AGENT);
  __syncthreads();
  agstore(&rimg[R0 * IMG + C0 + tid],              recS[swz(0, tid)]);
  agstore(&rimg[(R0 + TSZ - 1) * IMG + C0 + tid],  recS[swz(TSZ - 1, tid)]);
  agstore(&rimg[(R0 + tid) * IMG + C0],            recS[swz(tid, 0)]);
  agstore(&rimg[(R0 + tid) * IMG + C0 + TSZ - 1],  recS[swz(tid, TSZ - 1)]);
  img_barrier(bar, gen, tid);

  // ---- recon 3: R = rho(min(U, Rmax) | Rmax) ----
  recon(recS, maskS, topH, botH, leftH, rightH, rimg, &tag[2], bar, gen,
        R0, C0, tid, &blkflag);

  // ---- phase D: count U == R per image ----
  unsigned cnt = 0;
  for (int rr = 0; rr < TSZ; ++rr) {
    float Rv = recS[swz(rr, tid)];
    float uv = uimg[(R0 + rr) * IMG + C0 + tid] / 100.0f;
    cnt += (uv == Rv) ? 1u : 0u;
  }
  for (int off = 32; off > 0; off >>= 1) cnt += __shfl_down(cnt, off, 64);
  if ((tid & 63) == 0)
    __hip_atomic_fetch_add(&ctrl[34 + img], cnt, __ATOMIC_RELAXED, __HIP_MEMORY_SCOPE_AGENT);
  img_barrier(bar, gen, tid);  // all tiles' CC adds done

  if (tin == 0 && tid == 0)
    __hip_atomic_fetch_add(&ctrl[42], 1u, __ATOMIC_RELEASE, __HIP_MEMORY_SCOPE_AGENT);

  // ---- final join + output (block 0 only; co-resident via coop launch) ----
  if (blk == 0) {
    if (tid == 0) {
      while (__hip_atomic_load(&ctrl[42], __ATOMIC_RELAXED, __HIP_MEMORY_SCOPE_AGENT) < NIMG)
        __builtin_amdgcn_s_sleep(1);
    }
    __syncthreads();
    __threadfence();
    if (tid < NIMG) {
      float CC = (float)agloadu(&ctrl[34 + tid]);
      float gmax = agloadu(&ctrl[32]) ? 1.0f : 0.0f;
      float gmin = agloadu(&ctrl[33]) ? 0.0f : 1.0f;
      float d = gmax - gmin;
      out[tid] = fminf(CC, 100.0f * d * CC);
    }
  }
}

extern "C" void kernel_launch(void* const* d_in, const int* in_sizes, int n_in,
                              void* d_out, int out_size, void* d_ws, size_t ws_size,
                              hipStream_t stream) {
  const float* x = (const float*)d_in[0];
  const float* h = (const float*)d_in[1];
  const float* u = (const float*)d_in[2];
  float* out = (float*)d_out;
  float* rec_g = (float*)d_ws;
  unsigned* ctrl = (unsigned*)((char*)d_ws + (size_t)NIMG * IMG * IMG * sizeof(float));

  hipMemsetAsync(ctrl, 0, CTRL_WORDS * sizeof(unsigned), stream);

  const unsigned SH = (2 * TSZ * TSZ + 2 * (TSZ + 2) + 2 * TSZ) * sizeof(float);
  hipFuncSetAttribute((const void*)hmax_kernel,
                      hipFuncAttributeMaxDynamicSharedMemorySize, (int)SH);

  void* args[] = { (void*)&x, (void*)&h, (void*)&u, (void*)&out,
                   (void*)&rec_g, (void*)&ctrl };
  hipLaunchCooperativeKernel((void*)hmax_kernel, dim3(NBLK), dim3(TPB),
                             args, SH, stream);
}